// Round 1
// baseline (893.451 us; speedup 1.0000x reference)
//
#include <hip/hip_runtime.h>

namespace {
constexpr int Bb = 2;
constexpr int Nn = 2048;
constexpr int Cc = 768;
constexpr int Hh = 12;
constexpr int DH = 64;
constexpr float SCALE = 0.125f;   // DH^-0.5
}

#define F4AT(v, t) ((t) == 0 ? (v).x : ((t) == 1 ? (v).y : ((t) == 2 ? (v).z : (v).w)))

// ---------------------------------------------------------------------------
// Tiled fp32 GEMM: Cm[M,N] = A[M,K] @ Bm[K,N] (+ bias). 64x64 tile, BK=32,
// 256 threads (16x16), 4x4 microtile per thread.
// A tile stored transposed in LDS (pitch 68) so inner loop does ds_read_b128.
// ---------------------------------------------------------------------------
template <bool BIAS>
__global__ __launch_bounds__(256) void gemm64(const float* __restrict__ A,
                                              const float* __restrict__ Bm,
                                              const float* __restrict__ bias,
                                              float* __restrict__ Cm,
                                              int M, int N, int K) {
  __shared__ float Ast[32][68];  // [k][m] transposed, pitch 68 keeps 16B align
  __shared__ float Bs[32][64];   // [k][n]

  const int tx = threadIdx.x;    // 0..15
  const int ty = threadIdx.y;    // 0..15
  const int tid = ty * 16 + tx;
  const int m0 = blockIdx.y * 64;
  const int n0 = blockIdx.x * 64;

  float acc[4][4] = {};

  for (int k0 = 0; k0 < K; k0 += 32) {
    float4 av[2], bv[2];
    int ar[2], ac4[2], br[2], bc4[2];
#pragma unroll
    for (int q = 0; q < 2; ++q) {
      int f = q * 256 + tid;
      ar[q] = f >> 3;            // A tile: 64 rows x 32 cols, 8 float4 per row
      ac4[q] = f & 7;
      av[q] = *(const float4*)(A + (size_t)(m0 + ar[q]) * K + k0 + ac4[q] * 4);
      br[q] = f >> 4;            // B tile: 32 rows x 64 cols, 16 float4 per row
      bc4[q] = f & 15;
      bv[q] = *(const float4*)(Bm + (size_t)(k0 + br[q]) * N + n0 + bc4[q] * 4);
    }
    __syncthreads();             // previous compute done before overwrite
#pragma unroll
    for (int q = 0; q < 2; ++q) {
      Ast[ac4[q] * 4 + 0][ar[q]] = av[q].x;
      Ast[ac4[q] * 4 + 1][ar[q]] = av[q].y;
      Ast[ac4[q] * 4 + 2][ar[q]] = av[q].z;
      Ast[ac4[q] * 4 + 3][ar[q]] = av[q].w;
      *(float4*)&Bs[br[q]][bc4[q] * 4] = bv[q];
    }
    __syncthreads();
#pragma unroll 8
    for (int kk = 0; kk < 32; ++kk) {
      float4 a4 = *(const float4*)&Ast[kk][ty * 4];
      float4 b4 = *(const float4*)&Bs[kk][tx * 4];
      float a_[4] = {a4.x, a4.y, a4.z, a4.w};
      float b_[4] = {b4.x, b4.y, b4.z, b4.w};
#pragma unroll
      for (int i = 0; i < 4; ++i)
#pragma unroll
        for (int j = 0; j < 4; ++j)
          acc[i][j] = fmaf(a_[i], b_[j], acc[i][j]);
    }
  }

  float4 bi = make_float4(0.f, 0.f, 0.f, 0.f);
  if (BIAS) bi = *(const float4*)(bias + n0 + tx * 4);
#pragma unroll
  for (int i = 0; i < 4; ++i) {
    float4 ov;
    ov.x = acc[i][0] + bi.x;
    ov.y = acc[i][1] + bi.y;
    ov.z = acc[i][2] + bi.z;
    ov.w = acc[i][3] + bi.w;
    *(float4*)(Cm + (size_t)(m0 + ty * 4 + i) * N + n0 + tx * 4) = ov;
  }
}

// ---------------------------------------------------------------------------
// Flash attention, fp32. One block per (b, h, 64-row q tile). 256 threads.
// Online softmax (running m,l per row), row reductions via __shfl_xor over
// the 16 tx lanes (wave64 = 4 ty-groups x 16 tx). Gate folded into epilogue.
// qkv layout: [B, N, 3C] with q at col h*64, k at 768+h*64, v at 1536+h*64.
// ---------------------------------------------------------------------------
__global__ __launch_bounds__(256) void attn_fused(const float* __restrict__ qkv,
                                                  const float* __restrict__ gate,
                                                  float* __restrict__ attn_out) {
  __shared__ float Qst[64][68];  // [d][qrow], pre-scaled by SCALE
  __shared__ float Kst[64][68];  // [d][krow]
  __shared__ float Vs[64][68];   // [krow][d]
  __shared__ float Ps[64][65];   // [qrow][krow]

  const int tx = threadIdx.x, ty = threadIdx.y;
  const int tid = ty * 16 + tx;
  const int q0 = blockIdx.x * 64;
  const int h = blockIdx.y;
  const int b = blockIdx.z;

  const float* qb = qkv + (size_t)b * Nn * (3 * Cc) + h * DH;
  const float* kb = qb + Cc;
  const float* vb = qb + 2 * Cc;

  // Load Q tile (transposed, pre-scaled).
#pragma unroll
  for (int qq = 0; qq < 4; ++qq) {
    int f = qq * 256 + tid;
    int row = f >> 4, c4 = f & 15;
    float4 v = *(const float4*)(qb + (size_t)(q0 + row) * (3 * Cc) + c4 * 4);
    Qst[c4 * 4 + 0][row] = v.x * SCALE;
    Qst[c4 * 4 + 1][row] = v.y * SCALE;
    Qst[c4 * 4 + 2][row] = v.z * SCALE;
    Qst[c4 * 4 + 3][row] = v.w * SCALE;
  }

  float o[4][4] = {};
  float mrow[4] = {-1e30f, -1e30f, -1e30f, -1e30f};
  float lrow[4] = {};

  for (int kc = 0; kc < Nn; kc += 64) {
    // Issue global loads for K/V chunk before the barrier (overlap with PV).
    float4 kv[4], vv[4];
    int row_[4], c4_[4];
#pragma unroll
    for (int qq = 0; qq < 4; ++qq) {
      int f = qq * 256 + tid;
      row_[qq] = f >> 4;
      c4_[qq] = f & 15;
      const size_t off = (size_t)(kc + row_[qq]) * (3 * Cc) + c4_[qq] * 4;
      kv[qq] = *(const float4*)(kb + off);
      vv[qq] = *(const float4*)(vb + off);
    }
    __syncthreads();  // previous chunk's PV (Ps/Vs readers) done
#pragma unroll
    for (int qq = 0; qq < 4; ++qq) {
      Kst[c4_[qq] * 4 + 0][row_[qq]] = kv[qq].x;
      Kst[c4_[qq] * 4 + 1][row_[qq]] = kv[qq].y;
      Kst[c4_[qq] * 4 + 2][row_[qq]] = kv[qq].z;
      Kst[c4_[qq] * 4 + 3][row_[qq]] = kv[qq].w;
      *(float4*)&Vs[row_[qq]][c4_[qq] * 4] = vv[qq];
    }
    __syncthreads();

    // S = (Q*SCALE) @ K^T  -> s[i][j], rows r=ty*4+i, cols c=tx*4+j
    float s[4][4] = {};
#pragma unroll 8
    for (int d = 0; d < 64; ++d) {
      float4 q4 = *(const float4*)&Qst[d][ty * 4];
      float4 k4 = *(const float4*)&Kst[d][tx * 4];
      float a_[4] = {q4.x, q4.y, q4.z, q4.w};
      float b_[4] = {k4.x, k4.y, k4.z, k4.w};
#pragma unroll
      for (int i = 0; i < 4; ++i)
#pragma unroll
        for (int j = 0; j < 4; ++j)
          s[i][j] = fmaf(a_[i], b_[j], s[i][j]);
    }

    // Online softmax update.
    float pm[4], fac[4], rs[4];
#pragma unroll
    for (int i = 0; i < 4; ++i)
      pm[i] = fmaxf(fmaxf(s[i][0], s[i][1]), fmaxf(s[i][2], s[i][3]));
#pragma unroll
    for (int msk = 1; msk < 16; msk <<= 1)
#pragma unroll
      for (int i = 0; i < 4; ++i)
        pm[i] = fmaxf(pm[i], __shfl_xor(pm[i], msk, 64));
#pragma unroll
    for (int i = 0; i < 4; ++i) {
      float mn = fmaxf(mrow[i], pm[i]);
      fac[i] = __expf(mrow[i] - mn);
      mrow[i] = mn;
      float sum = 0.f;
#pragma unroll
      for (int j = 0; j < 4; ++j) {
        s[i][j] = __expf(s[i][j] - mn);
        sum += s[i][j];
      }
      rs[i] = sum;
    }
#pragma unroll
    for (int msk = 1; msk < 16; msk <<= 1)
#pragma unroll
      for (int i = 0; i < 4; ++i)
        rs[i] += __shfl_xor(rs[i], msk, 64);
#pragma unroll
    for (int i = 0; i < 4; ++i) {
      lrow[i] = lrow[i] * fac[i] + rs[i];
#pragma unroll
      for (int j = 0; j < 4; ++j) {
        o[i][j] *= fac[i];
        Ps[ty * 4 + i][tx * 4 + j] = s[i][j];
      }
    }
    __syncthreads();

    // O += P @ V   (o[i][j]: rows ty*4+i, dims tx*4+j)
#pragma unroll 4
    for (int c4 = 0; c4 < 16; ++c4) {
      float4 p4[4], v4[4];
#pragma unroll
      for (int i = 0; i < 4; ++i) p4[i] = *(const float4*)&Ps[ty * 4 + i][c4 * 4];
#pragma unroll
      for (int t = 0; t < 4; ++t) v4[t] = *(const float4*)&Vs[c4 * 4 + t][tx * 4];
#pragma unroll
      for (int t = 0; t < 4; ++t) {
        float vt[4] = {v4[t].x, v4[t].y, v4[t].z, v4[t].w};
#pragma unroll
        for (int i = 0; i < 4; ++i) {
          float p = F4AT(p4[i], t);
#pragma unroll
          for (int j = 0; j < 4; ++j)
            o[i][j] = fmaf(p, vt[j], o[i][j]);
        }
      }
    }
  }

  // Epilogue: normalize, apply per-head gate, write [B,N,C] merged heads.
  const float g = gate[h];
#pragma unroll
  for (int i = 0; i < 4; ++i) {
    float inv = g / lrow[i];
    float4 ov = make_float4(o[i][0] * inv, o[i][1] * inv, o[i][2] * inv, o[i][3] * inv);
    *(float4*)(attn_out + (size_t)(b * Nn + q0 + ty * 4 + i) * Cc + h * DH + tx * 4) = ov;
  }
}

// ---------------------------------------------------------------------------
extern "C" void kernel_launch(void* const* d_in, const int* in_sizes, int n_in,
                              void* d_out, int out_size, void* d_ws, size_t ws_size,
                              hipStream_t stream) {
  const float* x      = (const float*)d_in[0];  // [B,N,C]
  const float* w_qkv  = (const float*)d_in[1];  // [C,3C]
  const float* gate   = (const float*)d_in[2];  // [H]
  const float* w_proj = (const float*)d_in[3];  // [C,C]
  const float* b_proj = (const float*)d_in[4];  // [C]
  float* out = (float*)d_out;                   // [B,N,C]

  float* qkv      = (float*)d_ws;                        // [4096, 2304]
  float* attn_out = qkv + (size_t)(Bb * Nn) * (3 * Cc);  // [4096, 768]

  dim3 blk(16, 16);

  // qkv = x @ w_qkv : [4096,768] @ [768,2304]
  gemm64<false><<<dim3((3 * Cc) / 64, (Bb * Nn) / 64), blk, 0, stream>>>(
      x, w_qkv, nullptr, qkv, Bb * Nn, 3 * Cc, Cc);

  // fused flash attention + gate -> attn_out [4096, 768]
  attn_fused<<<dim3(Nn / 64, Hh, Bb), blk, 0, stream>>>(qkv, gate, attn_out);

  // out = attn_out @ w_proj + b_proj : [4096,768] @ [768,768]
  gemm64<true><<<dim3(Cc / 64, (Bb * Nn) / 64), blk, 0, stream>>>(
      attn_out, w_proj, b_proj, out, Bb * Nn, Cc, Cc);
}

// Round 2
// 484.672 us; speedup vs baseline: 1.8434x; 1.8434x over previous
//
#include <hip/hip_runtime.h>
#include <cstdint>
#include <cstddef>

typedef uint16_t u16;
typedef uint32_t u32;
using f32x4 = __attribute__((ext_vector_type(4))) float;
using s16x8 = __attribute__((ext_vector_type(8))) short;

#define MFMA(a, b, c) __builtin_amdgcn_mfma_f32_16x16x32_bf16((a), (b), (c), 0, 0, 0)

// XOR swizzle for [R][64] bf16 LDS tiles (u16 index units): keeps 16B blocks
// intact (bits 3..5), spreads rows across bank slots -> conflict-free b128.
#define SWZ(r, c) ((((r) * 64) + (c)) ^ (((r) & 7) << 3))

__device__ __forceinline__ u16 f2bf(float f) {
  u32 u = __builtin_bit_cast(u32, f);
  u += 0x7FFFu + ((u >> 16) & 1u);
  return (u16)(u >> 16);
}
__device__ __forceinline__ float bf2f(u16 h) {
  u32 u = ((u32)h) << 16;
  return __builtin_bit_cast(float, u);
}

// ---------------------------------------------------------------------------
// Split fp32 -> bf16 hi + bf16 lo (residual), 8 elements/thread.
// ---------------------------------------------------------------------------
__global__ void split8(const float* __restrict__ in, u16* __restrict__ hi,
                       u16* __restrict__ lo, int n8) {
  int i = blockIdx.x * 256 + threadIdx.x;
  if (i >= n8) return;
  const float4* p4 = (const float4*)in;
  float4 a = p4[2 * i], b = p4[2 * i + 1];
  float v[8] = {a.x, a.y, a.z, a.w, b.x, b.y, b.z, b.w};
  u32 hw[4], lw[4];
#pragma unroll
  for (int j = 0; j < 4; ++j) {
    u16 h0 = f2bf(v[2 * j]), h1 = f2bf(v[2 * j + 1]);
    u16 l0 = f2bf(v[2 * j] - bf2f(h0)), l1 = f2bf(v[2 * j + 1] - bf2f(h1));
    hw[j] = (u32)h0 | ((u32)h1 << 16);
    lw[j] = (u32)l0 | ((u32)l1 << 16);
  }
  ((uint4*)hi)[i] = make_uint4(hw[0], hw[1], hw[2], hw[3]);
  ((uint4*)lo)[i] = make_uint4(lw[0], lw[1], lw[2], lw[3]);
}

// ---------------------------------------------------------------------------
// Split + transpose: in [K][N] fp32 -> out_h/out_l [N][K] bf16.
// ---------------------------------------------------------------------------
__global__ void splitT(const float* __restrict__ in, u16* __restrict__ th,
                       u16* __restrict__ tl, int K, int N) {
  __shared__ float t[32][33];
  const int n0 = blockIdx.x * 32, k0 = blockIdx.y * 32;
  const int tx = threadIdx.x, ty = threadIdx.y;
#pragma unroll
  for (int q = 0; q < 4; ++q)
    t[ty + 8 * q][tx] = in[(size_t)(k0 + ty + 8 * q) * N + n0 + tx];
  __syncthreads();
#pragma unroll
  for (int q = 0; q < 4; ++q) {
    float v = t[tx][ty + 8 * q];
    u16 h = f2bf(v);
    size_t oi = (size_t)(n0 + ty + 8 * q) * K + k0 + tx;
    th[oi] = h;
    tl[oi] = f2bf(v - bf2f(h));
  }
}

// ---------------------------------------------------------------------------
// Split-bf16 GEMM: C[M,N] = A[M,K] @ B[K,N], A as (Ah+Al), B given TRANSPOSED
// [N][K] as (BTh+BTl). 3-product MFMA (hh + hl + lh). 128x128 tile, BK=32,
// 256 threads = 4 waves (2x2), each wave 64x64 = 4x4 fragments of 16x16x32.
// MODE 0: write bf16 hi/lo pair + side-write transposed V block (cols>=1536).
// MODE 1: write fp32 + bias.
// ---------------------------------------------------------------------------
template <int MODE>
__global__ __launch_bounds__(256, 3) void gemm_split(
    const u16* __restrict__ Ah, const u16* __restrict__ Al,
    const u16* __restrict__ BTh, const u16* __restrict__ BTl,
    u16* __restrict__ Ch, u16* __restrict__ Cl,
    u16* __restrict__ vTh, u16* __restrict__ vTl,
    float* __restrict__ Cf, const float* __restrict__ bias,
    int N, int K) {
  __shared__ u16 Ash[128 * 40], Asl[128 * 40], Bsh[128 * 40], Bsl[128 * 40];

  const int tid = threadIdx.x;
  const int wave = tid >> 6, lane = tid & 63;
  const int lr = lane & 15, lg = lane >> 4;
  const int wm = (wave >> 1) * 64, wn = (wave & 1) * 64;
  const int m0 = blockIdx.y * 128, n0 = blockIdx.x * 128;

  const int r0 = tid >> 2;   // 0..63 (row within half-tile)
  const int g0 = tid & 3;    // 16B chunk within 32-k row

  const u16* pAh = Ah + (size_t)(m0 + r0) * K + g0 * 8;
  const u16* pAl = Al + (size_t)(m0 + r0) * K + g0 * 8;
  const u16* pBh = BTh + (size_t)(n0 + r0) * K + g0 * 8;
  const u16* pBl = BTl + (size_t)(n0 + r0) * K + g0 * 8;
  const size_t rstep = (size_t)64 * K;
  const int li0 = r0 * 40 + g0 * 8, li1 = (64 + r0) * 40 + g0 * 8;

  const f32x4 fz = {0.f, 0.f, 0.f, 0.f};
  f32x4 acc[4][4];
#pragma unroll
  for (int i = 0; i < 4; ++i)
#pragma unroll
    for (int j = 0; j < 4; ++j) acc[i][j] = fz;

  for (int k0 = 0; k0 < K; k0 += 32) {
    uint4 ah0 = *(const uint4*)(pAh + k0);
    uint4 ah1 = *(const uint4*)(pAh + rstep + k0);
    uint4 al0 = *(const uint4*)(pAl + k0);
    uint4 al1 = *(const uint4*)(pAl + rstep + k0);
    uint4 bh0 = *(const uint4*)(pBh + k0);
    uint4 bh1 = *(const uint4*)(pBh + rstep + k0);
    uint4 bl0 = *(const uint4*)(pBl + k0);
    uint4 bl1 = *(const uint4*)(pBl + rstep + k0);
    __syncthreads();
    *(uint4*)&Ash[li0] = ah0;
    *(uint4*)&Ash[li1] = ah1;
    *(uint4*)&Asl[li0] = al0;
    *(uint4*)&Asl[li1] = al1;
    *(uint4*)&Bsh[li0] = bh0;
    *(uint4*)&Bsh[li1] = bh1;
    *(uint4*)&Bsl[li0] = bl0;
    *(uint4*)&Bsl[li1] = bl1;
    __syncthreads();

    s16x8 a_h[4], a_l[4];
#pragma unroll
    for (int i = 0; i < 4; ++i) {
      a_h[i] = *(const s16x8*)&Ash[(wm + i * 16 + lr) * 40 + lg * 8];
      a_l[i] = *(const s16x8*)&Asl[(wm + i * 16 + lr) * 40 + lg * 8];
    }
#pragma unroll
    for (int j = 0; j < 4; ++j) {
      s16x8 b_h = *(const s16x8*)&Bsh[(wn + j * 16 + lr) * 40 + lg * 8];
      s16x8 b_l = *(const s16x8*)&Bsl[(wn + j * 16 + lr) * 40 + lg * 8];
#pragma unroll
      for (int i = 0; i < 4; ++i) {
        acc[i][j] = MFMA(a_h[i], b_h, acc[i][j]);
        acc[i][j] = MFMA(a_h[i], b_l, acc[i][j]);
        acc[i][j] = MFMA(a_l[i], b_h, acc[i][j]);
      }
    }
  }

#pragma unroll
  for (int i = 0; i < 4; ++i)
#pragma unroll
    for (int r = 0; r < 4; ++r) {
      const int row = m0 + wm + i * 16 + lg * 4 + r;
#pragma unroll
      for (int j = 0; j < 4; ++j) {
        const int col = n0 + wn + j * 16 + lr;
        const float v = acc[i][j][r];
        if constexpr (MODE == 0) {
          u16 hh = f2bf(v);
          u16 ll = f2bf(v - bf2f(hh));
          Ch[(size_t)row * N + col] = hh;
          Cl[(size_t)row * N + col] = ll;
          if (n0 >= 1536) {  // V block: also store transposed per (b,h)
            int vc = col - 1536;
            int hd = vc >> 6, dd = vc & 63;
            size_t vidx =
                ((size_t)((row >> 11) * 12 + hd) * 64 + dd) * 2048 + (row & 2047);
            vTh[vidx] = hh;
            vTl[vidx] = ll;
          }
        } else {
          Cf[(size_t)row * N + col] = v + bias[col];
        }
      }
    }
}

// ---------------------------------------------------------------------------
// Flash attention, split-bf16 MFMA. Block = (b, h, 64 q-rows), 4 waves each
// owning 16 q-rows. K/V chunk = 64. Q,K from qkv hi/lo; V from pre-transposed
// vT hi/lo. P staged per-wave in LDS as bf16 hi/lo. Gate in epilogue.
// ---------------------------------------------------------------------------
__global__ __launch_bounds__(256, 3) void attn_split(
    const u16* __restrict__ qkvh, const u16* __restrict__ qkvl,
    const u16* __restrict__ vth, const u16* __restrict__ vtl,
    const float* __restrict__ gate,
    u16* __restrict__ aoh, u16* __restrict__ aol) {
  __shared__ u16 Ksh[4096], Ksl[4096], Vsh[4096], Vsl[4096];
  __shared__ u16 Ph[4][1024], Pl[4][1024];

  const int tid = threadIdx.x;
  const int wave = tid >> 6, lane = tid & 63;
  const int lr = lane & 15, lg = lane >> 4;
  const int q0 = blockIdx.x * 64;
  const int hh = blockIdx.y;
  const int bb = blockIdx.z;
  const int sc8 = tid & 7;

  // ---- stage Q tile (rows q0..q0+63) into Ksh/Ksl, read A-fragments ----
#pragma unroll
  for (int q = 0; q < 2; ++q) {
    int row = q * 32 + (tid >> 3);
    size_t ga = (size_t)(bb * 2048 + q0 + row) * 2304 + hh * 64 + sc8 * 8;
    uint4 vh = *(const uint4*)(qkvh + ga);
    uint4 vl = *(const uint4*)(qkvl + ga);
    *(uint4*)&Ksh[SWZ(row, sc8 * 8)] = vh;
    *(uint4*)&Ksl[SWZ(row, sc8 * 8)] = vl;
  }
  __syncthreads();
  s16x8 Qh[2], Ql[2];
#pragma unroll
  for (int ks = 0; ks < 2; ++ks) {
    Qh[ks] = *(const s16x8*)&Ksh[SWZ(wave * 16 + lr, ks * 32 + lg * 8)];
    Ql[ks] = *(const s16x8*)&Ksl[SWZ(wave * 16 + lr, ks * 32 + lg * 8)];
  }

  const f32x4 fz = {0.f, 0.f, 0.f, 0.f};
  f32x4 o[4] = {fz, fz, fz, fz};
  float mrow[4] = {-3e38f, -3e38f, -3e38f, -3e38f};
  float lrow[4] = {0.f, 0.f, 0.f, 0.f};

  for (int kc = 0; kc < 2048; kc += 64) {
    uint4 kh[2], kl[2], vh[2], vl[2];
#pragma unroll
    for (int q = 0; q < 2; ++q) {
      int row = q * 32 + (tid >> 3);
      size_t gk = (size_t)(bb * 2048 + kc + row) * 2304 + 768 + hh * 64 + sc8 * 8;
      size_t gv = (size_t)((bb * 12 + hh) * 64 + row) * 2048 + kc + sc8 * 8;
      kh[q] = *(const uint4*)(qkvh + gk);
      kl[q] = *(const uint4*)(qkvl + gk);
      vh[q] = *(const uint4*)(vth + gv);
      vl[q] = *(const uint4*)(vtl + gv);
    }
    __syncthreads();  // previous chunk's compute done
#pragma unroll
    for (int q = 0; q < 2; ++q) {
      int row = q * 32 + (tid >> 3);
      int li = SWZ(row, sc8 * 8);
      *(uint4*)&Ksh[li] = kh[q];
      *(uint4*)&Ksl[li] = kl[q];
      *(uint4*)&Vsh[li] = vh[q];
      *(uint4*)&Vsl[li] = vl[q];
    }
    __syncthreads();

    // S = (Q K^T) * SCALE : s[f] holds rows lg*4+r, cols f*16+lr
    f32x4 s[4];
#pragma unroll
    for (int f = 0; f < 4; ++f) {
      s[f] = fz;
#pragma unroll
      for (int ks = 0; ks < 2; ++ks) {
        s16x8 kbh = *(const s16x8*)&Ksh[SWZ(f * 16 + lr, ks * 32 + lg * 8)];
        s16x8 kbl = *(const s16x8*)&Ksl[SWZ(f * 16 + lr, ks * 32 + lg * 8)];
        s[f] = MFMA(Qh[ks], kbh, s[f]);
        s[f] = MFMA(Qh[ks], kbl, s[f]);
        s[f] = MFMA(Ql[ks], kbh, s[f]);
      }
    }
    float pm[4];
#pragma unroll
    for (int r = 0; r < 4; ++r) {
#pragma unroll
      for (int f = 0; f < 4; ++f) s[f][r] *= 0.125f;
      pm[r] = fmaxf(fmaxf(s[0][r], s[1][r]), fmaxf(s[2][r], s[3][r]));
    }
#pragma unroll
    for (int msk = 1; msk < 16; msk <<= 1)
#pragma unroll
      for (int r = 0; r < 4; ++r)
        pm[r] = fmaxf(pm[r], __shfl_xor(pm[r], msk, 64));
    float fac[4], psum[4];
#pragma unroll
    for (int r = 0; r < 4; ++r) {
      float mn = fmaxf(mrow[r], pm[r]);
      fac[r] = __expf(mrow[r] - mn);
      mrow[r] = mn;
      psum[r] = 0.f;
    }
#pragma unroll
    for (int f = 0; f < 4; ++f)
#pragma unroll
      for (int r = 0; r < 4; ++r) {
        float pv = __expf(s[f][r] - mrow[r]);
        psum[r] += pv;
        u16 p_h = f2bf(pv);
        u16 p_l = f2bf(pv - bf2f(p_h));
        int pi = SWZ(lg * 4 + r, f * 16 + lr);
        Ph[wave][pi] = p_h;
        Pl[wave][pi] = p_l;
      }
#pragma unroll
    for (int msk = 1; msk < 16; msk <<= 1)
#pragma unroll
      for (int r = 0; r < 4; ++r)
        psum[r] += __shfl_xor(psum[r], msk, 64);
#pragma unroll
    for (int r = 0; r < 4; ++r) {
      lrow[r] = lrow[r] * fac[r] + psum[r];
#pragma unroll
      for (int nf = 0; nf < 4; ++nf) o[nf][r] *= fac[r];
    }

    // O += P @ V  (P rows private to this wave; in-wave LDS ordering)
    s16x8 pah[2], pal[2];
#pragma unroll
    for (int ks = 0; ks < 2; ++ks) {
      pah[ks] = *(const s16x8*)&Ph[wave][SWZ(lr, ks * 32 + lg * 8)];
      pal[ks] = *(const s16x8*)&Pl[wave][SWZ(lr, ks * 32 + lg * 8)];
    }
#pragma unroll
    for (int nf = 0; nf < 4; ++nf) {
#pragma unroll
      for (int ks = 0; ks < 2; ++ks) {
        s16x8 vbh = *(const s16x8*)&Vsh[SWZ(nf * 16 + lr, ks * 32 + lg * 8)];
        s16x8 vbl = *(const s16x8*)&Vsl[SWZ(nf * 16 + lr, ks * 32 + lg * 8)];
        o[nf] = MFMA(pah[ks], vbh, o[nf]);
        o[nf] = MFMA(pah[ks], vbl, o[nf]);
        o[nf] = MFMA(pal[ks], vbh, o[nf]);
      }
    }
  }

  const float gv = gate[hh];
#pragma unroll
  for (int r = 0; r < 4; ++r) {
    float inv = gv / lrow[r];
    int row = bb * 2048 + q0 + wave * 16 + lg * 4 + r;
#pragma unroll
    for (int nf = 0; nf < 4; ++nf) {
      float v = o[nf][r] * inv;
      int col = hh * 64 + nf * 16 + lr;
      u16 vh16 = f2bf(v);
      aoh[(size_t)row * 768 + col] = vh16;
      aol[(size_t)row * 768 + col] = f2bf(v - bf2f(vh16));
    }
  }
}

// ---------------------------------------------------------------------------
extern "C" void kernel_launch(void* const* d_in, const int* in_sizes, int n_in,
                              void* d_out, int out_size, void* d_ws, size_t ws_size,
                              hipStream_t stream) {
  const float* x = (const float*)d_in[0];
  const float* w_qkv = (const float*)d_in[1];
  const float* gate = (const float*)d_in[2];
  const float* w_proj = (const float*)d_in[3];
  const float* b_proj = (const float*)d_in[4];
  float* out = (float*)d_out;

  u16* p = (u16*)d_ws;
  u16* xh = p; p += (size_t)4096 * 768;
  u16* xl = p; p += (size_t)4096 * 768;
  u16* wqh = p; p += (size_t)2304 * 768;
  u16* wql = p; p += (size_t)2304 * 768;
  u16* wph = p; p += (size_t)768 * 768;
  u16* wpl = p; p += (size_t)768 * 768;
  u16* qh = p; p += (size_t)4096 * 2304;
  u16* ql = p; p += (size_t)4096 * 2304;
  u16* vth = p; p += (size_t)24 * 64 * 2048;
  u16* vtl = p; p += (size_t)24 * 64 * 2048;
  u16* aoh = p; p += (size_t)4096 * 768;
  u16* aol = p; p += (size_t)4096 * 768;

  split8<<<dim3(4096 * 768 / 8 / 256), dim3(256), 0, stream>>>(x, xh, xl, 4096 * 768 / 8);
  splitT<<<dim3(2304 / 32, 768 / 32), dim3(32, 8), 0, stream>>>(w_qkv, wqh, wql, 768, 2304);
  splitT<<<dim3(768 / 32, 768 / 32), dim3(32, 8), 0, stream>>>(w_proj, wph, wpl, 768, 768);

  gemm_split<0><<<dim3(2304 / 128, 4096 / 128), dim3(256), 0, stream>>>(
      xh, xl, wqh, wql, qh, ql, vth, vtl, nullptr, nullptr, 2304, 768);

  attn_split<<<dim3(32, 12, 2), dim3(256), 0, stream>>>(qh, ql, vth, vtl, gate, aoh, aol);

  gemm_split<1><<<dim3(768 / 128, 4096 / 128), dim3(256), 0, stream>>>(
      aoh, aol, wph, wpl, nullptr, nullptr, nullptr, nullptr, out, b_proj, 768, 768);
}

// Round 3
// 441.927 us; speedup vs baseline: 2.0217x; 1.0967x over previous
//
#include <hip/hip_runtime.h>
#include <cstdint>
#include <cstddef>

typedef uint16_t u16;
typedef uint32_t u32;
using f32x4 = __attribute__((ext_vector_type(4))) float;
using s16x8 = __attribute__((ext_vector_type(8))) short;

#define MFMA(a, b, c) __builtin_amdgcn_mfma_f32_16x16x32_bf16((a), (b), (c), 0, 0, 0)

// XOR swizzle for [R][64] bf16 LDS tiles (u16 index units): keeps 16B blocks
// intact, spreads rows across bank slots -> conflict-free b128 access.
#define SWZ(r, c) ((((r) * 64) + (c)) ^ (((r) & 7) << 3))

__device__ __forceinline__ u16 f2bf(float f) {
  u32 u = __builtin_bit_cast(u32, f);
  u += 0x7FFFu + ((u >> 16) & 1u);
  return (u16)(u >> 16);
}
__device__ __forceinline__ float bf2f(u16 h) {
  u32 u = ((u32)h) << 16;
  return __builtin_bit_cast(float, u);
}

// ---------------------------------------------------------------------------
// Split fp32 -> bf16 hi + bf16 lo (residual), 8 elements/thread.
// ---------------------------------------------------------------------------
__global__ void split8(const float* __restrict__ in, u16* __restrict__ hi,
                       u16* __restrict__ lo, int n8) {
  int i = blockIdx.x * 256 + threadIdx.x;
  if (i >= n8) return;
  const float4* p4 = (const float4*)in;
  float4 a = p4[2 * i], b = p4[2 * i + 1];
  float v[8] = {a.x, a.y, a.z, a.w, b.x, b.y, b.z, b.w};
  u32 hw[4], lw[4];
#pragma unroll
  for (int j = 0; j < 4; ++j) {
    u16 h0 = f2bf(v[2 * j]), h1 = f2bf(v[2 * j + 1]);
    u16 l0 = f2bf(v[2 * j] - bf2f(h0)), l1 = f2bf(v[2 * j + 1] - bf2f(h1));
    hw[j] = (u32)h0 | ((u32)h1 << 16);
    lw[j] = (u32)l0 | ((u32)l1 << 16);
  }
  ((uint4*)hi)[i] = make_uint4(hw[0], hw[1], hw[2], hw[3]);
  ((uint4*)lo)[i] = make_uint4(lw[0], lw[1], lw[2], lw[3]);
}

// ---------------------------------------------------------------------------
// Split + transpose: in [K][N] fp32 -> out_h/out_l [N][K] bf16.
// ---------------------------------------------------------------------------
__global__ void splitT(const float* __restrict__ in, u16* __restrict__ th,
                       u16* __restrict__ tl, int K, int N) {
  __shared__ float t[32][33];
  const int n0 = blockIdx.x * 32, k0 = blockIdx.y * 32;
  const int tx = threadIdx.x, ty = threadIdx.y;
#pragma unroll
  for (int q = 0; q < 4; ++q)
    t[ty + 8 * q][tx] = in[(size_t)(k0 + ty + 8 * q) * N + n0 + tx];
  __syncthreads();
#pragma unroll
  for (int q = 0; q < 4; ++q) {
    float v = t[tx][ty + 8 * q];
    u16 h = f2bf(v);
    size_t oi = (size_t)(n0 + ty + 8 * q) * K + k0 + tx;
    th[oi] = h;
    tl[oi] = f2bf(v - bf2f(h));
  }
}

// ---------------------------------------------------------------------------
// Coalesced V transpose: qkv V block [N][DH] -> vT [(b,h,d)][N] per head.
// LDS tile 64x64, swizzled b128 writes, scalar transposed reads, uint4 out.
// ---------------------------------------------------------------------------
__global__ __launch_bounds__(256) void vtrans(const u16* __restrict__ qkvh,
                                              const u16* __restrict__ qkvl,
                                              u16* __restrict__ vth,
                                              u16* __restrict__ vtl) {
  __shared__ u16 th[4096], tl[4096];
  const int tid = threadIdx.x;
  const int kv0 = blockIdx.x * 64;
  const int hh = blockIdx.y, bb = blockIdx.z;
  const int sc8 = tid & 7, srow = tid >> 3;  // srow 0..31
#pragma unroll
  for (int q = 0; q < 2; ++q) {
    int row = q * 32 + srow;
    size_t ga = (size_t)(bb * 2048 + kv0 + row) * 2304 + 1536 + hh * 64 + sc8 * 8;
    *(uint4*)&th[SWZ(row, sc8 * 8)] = *(const uint4*)(qkvh + ga);
    *(uint4*)&tl[SWZ(row, sc8 * 8)] = *(const uint4*)(qkvl + ga);
  }
  __syncthreads();
#pragma unroll
  for (int q = 0; q < 2; ++q) {
    int d = q * 32 + srow;  // output row = head dim
    u32 hw[4], lw[4];
#pragma unroll
    for (int j = 0; j < 4; ++j) {
      int kv = sc8 * 8 + 2 * j;
      u16 h0 = th[SWZ(kv, d)], h1 = th[SWZ(kv + 1, d)];
      u16 l0 = tl[SWZ(kv, d)], l1 = tl[SWZ(kv + 1, d)];
      hw[j] = (u32)h0 | ((u32)h1 << 16);
      lw[j] = (u32)l0 | ((u32)l1 << 16);
    }
    size_t go = (size_t)((bb * 12 + hh) * 64 + d) * 2048 + kv0 + sc8 * 8;
    *(uint4*)(vth + go) = make_uint4(hw[0], hw[1], hw[2], hw[3]);
    *(uint4*)(vtl + go) = make_uint4(lw[0], lw[1], lw[2], lw[3]);
  }
}

// ---------------------------------------------------------------------------
// Split-bf16 GEMM: C[M,N] = A[M,K] @ B[K,N], B given TRANSPOSED [N][K].
// 3-product MFMA (hh + hl + lh). 128x128 tile, BK=32, 256 threads = 4 waves.
// MODE 0: write bf16 hi/lo pair. MODE 1: write fp32 + bias.
// ---------------------------------------------------------------------------
template <int MODE>
__global__ __launch_bounds__(256, 3) void gemm_split(
    const u16* __restrict__ Ah, const u16* __restrict__ Al,
    const u16* __restrict__ BTh, const u16* __restrict__ BTl,
    u16* __restrict__ Ch, u16* __restrict__ Cl,
    float* __restrict__ Cf, const float* __restrict__ bias,
    int N, int K) {
  __shared__ u16 Ash[128 * 40], Asl[128 * 40], Bsh[128 * 40], Bsl[128 * 40];

  const int tid = threadIdx.x;
  const int wave = tid >> 6, lane = tid & 63;
  const int lr = lane & 15, lg = lane >> 4;
  const int wm = (wave >> 1) * 64, wn = (wave & 1) * 64;
  const int m0 = blockIdx.y * 128, n0 = blockIdx.x * 128;

  const int r0 = tid >> 2;
  const int g0 = tid & 3;

  const u16* pAh = Ah + (size_t)(m0 + r0) * K + g0 * 8;
  const u16* pAl = Al + (size_t)(m0 + r0) * K + g0 * 8;
  const u16* pBh = BTh + (size_t)(n0 + r0) * K + g0 * 8;
  const u16* pBl = BTl + (size_t)(n0 + r0) * K + g0 * 8;
  const size_t rstep = (size_t)64 * K;
  const int li0 = r0 * 40 + g0 * 8, li1 = (64 + r0) * 40 + g0 * 8;

  const f32x4 fz = {0.f, 0.f, 0.f, 0.f};
  f32x4 acc[4][4];
#pragma unroll
  for (int i = 0; i < 4; ++i)
#pragma unroll
    for (int j = 0; j < 4; ++j) acc[i][j] = fz;

  for (int k0 = 0; k0 < K; k0 += 32) {
    uint4 ah0 = *(const uint4*)(pAh + k0);
    uint4 ah1 = *(const uint4*)(pAh + rstep + k0);
    uint4 al0 = *(const uint4*)(pAl + k0);
    uint4 al1 = *(const uint4*)(pAl + rstep + k0);
    uint4 bh0 = *(const uint4*)(pBh + k0);
    uint4 bh1 = *(const uint4*)(pBh + rstep + k0);
    uint4 bl0 = *(const uint4*)(pBl + k0);
    uint4 bl1 = *(const uint4*)(pBl + rstep + k0);
    __syncthreads();
    *(uint4*)&Ash[li0] = ah0;
    *(uint4*)&Ash[li1] = ah1;
    *(uint4*)&Asl[li0] = al0;
    *(uint4*)&Asl[li1] = al1;
    *(uint4*)&Bsh[li0] = bh0;
    *(uint4*)&Bsh[li1] = bh1;
    *(uint4*)&Bsl[li0] = bl0;
    *(uint4*)&Bsl[li1] = bl1;
    __syncthreads();

    s16x8 a_h[4], a_l[4];
#pragma unroll
    for (int i = 0; i < 4; ++i) {
      a_h[i] = *(const s16x8*)&Ash[(wm + i * 16 + lr) * 40 + lg * 8];
      a_l[i] = *(const s16x8*)&Asl[(wm + i * 16 + lr) * 40 + lg * 8];
    }
    __builtin_amdgcn_s_setprio(1);
#pragma unroll
    for (int j = 0; j < 4; ++j) {
      s16x8 b_h = *(const s16x8*)&Bsh[(wn + j * 16 + lr) * 40 + lg * 8];
      s16x8 b_l = *(const s16x8*)&Bsl[(wn + j * 16 + lr) * 40 + lg * 8];
#pragma unroll
      for (int i = 0; i < 4; ++i) {
        acc[i][j] = MFMA(a_h[i], b_h, acc[i][j]);
        acc[i][j] = MFMA(a_h[i], b_l, acc[i][j]);
        acc[i][j] = MFMA(a_l[i], b_h, acc[i][j]);
      }
    }
    __builtin_amdgcn_s_setprio(0);
  }

#pragma unroll
  for (int i = 0; i < 4; ++i)
#pragma unroll
    for (int r = 0; r < 4; ++r) {
      const int row = m0 + wm + i * 16 + lg * 4 + r;
#pragma unroll
      for (int j = 0; j < 4; ++j) {
        const int col = n0 + wn + j * 16 + lr;
        const float v = acc[i][j][r];
        if constexpr (MODE == 0) {
          u16 hh = f2bf(v);
          Ch[(size_t)row * N + col] = hh;
          Cl[(size_t)row * N + col] = f2bf(v - bf2f(hh));
        } else {
          Cf[(size_t)row * N + col] = v + bias[col];
        }
      }
    }
}

// ---------------------------------------------------------------------------
// Flash attention, split-bf16 MFMA. Block = (b, h, 64 q-rows), 4 waves each
// owning 16 q-rows. K/V chunk = 64, software-pipelined K/V register prefetch.
// QK^T at 3 products; PV at 2 products (P-lo dropped; psum from rounded P
// keeps numerator/denominator consistent). Gate folded into epilogue.
// ---------------------------------------------------------------------------
__global__ __launch_bounds__(256, 3) void attn_split(
    const u16* __restrict__ qkvh, const u16* __restrict__ qkvl,
    const u16* __restrict__ vth, const u16* __restrict__ vtl,
    const float* __restrict__ gate,
    u16* __restrict__ aoh, u16* __restrict__ aol) {
  __shared__ u16 Ksh[4096], Ksl[4096], Vsh[4096], Vsl[4096];
  __shared__ u16 Ph[4][1024];

  const int tid = threadIdx.x;
  const int wave = tid >> 6, lane = tid & 63;
  const int lr = lane & 15, lg = lane >> 4;
  const int q0 = blockIdx.x * 64;
  const int hh = blockIdx.y;
  const int bb = blockIdx.z;
  const int sc8 = tid & 7, srow = tid >> 3;  // srow 0..31

  // ---- stage Q tile into Ksh/Ksl, read resident A-fragments ----
#pragma unroll
  for (int q = 0; q < 2; ++q) {
    int row = q * 32 + srow;
    size_t ga = (size_t)(bb * 2048 + q0 + row) * 2304 + hh * 64 + sc8 * 8;
    *(uint4*)&Ksh[SWZ(row, sc8 * 8)] = *(const uint4*)(qkvh + ga);
    *(uint4*)&Ksl[SWZ(row, sc8 * 8)] = *(const uint4*)(qkvl + ga);
  }
  __syncthreads();
  s16x8 Qh[2], Ql[2];
#pragma unroll
  for (int ks = 0; ks < 2; ++ks) {
    Qh[ks] = *(const s16x8*)&Ksh[SWZ(wave * 16 + lr, ks * 32 + lg * 8)];
    Ql[ks] = *(const s16x8*)&Ksl[SWZ(wave * 16 + lr, ks * 32 + lg * 8)];
  }

  const f32x4 fz = {0.f, 0.f, 0.f, 0.f};
  f32x4 o[4] = {fz, fz, fz, fz};
  float mrow[4] = {-3e38f, -3e38f, -3e38f, -3e38f};
  float lrow[4] = {0.f, 0.f, 0.f, 0.f};

  uint4 kh[2], kl[2], vh[2], vl[2];
  auto loadc = [&](int kc) {
#pragma unroll
    for (int q = 0; q < 2; ++q) {
      int row = q * 32 + srow;
      size_t gk = (size_t)(bb * 2048 + kc + row) * 2304 + 768 + hh * 64 + sc8 * 8;
      size_t gv = (size_t)((bb * 12 + hh) * 64 + row) * 2048 + kc + sc8 * 8;
      kh[q] = *(const uint4*)(qkvh + gk);
      kl[q] = *(const uint4*)(qkvl + gk);
      vh[q] = *(const uint4*)(vth + gv);
      vl[q] = *(const uint4*)(vtl + gv);
    }
  };
  loadc(0);

  for (int kc = 0; kc < 2048; kc += 64) {
    __syncthreads();  // previous chunk's LDS readers done
#pragma unroll
    for (int q = 0; q < 2; ++q) {
      int li = SWZ(q * 32 + srow, sc8 * 8);
      *(uint4*)&Ksh[li] = kh[q];
      *(uint4*)&Ksl[li] = kl[q];
      *(uint4*)&Vsh[li] = vh[q];
      *(uint4*)&Vsl[li] = vl[q];
    }
    __syncthreads();
    if (kc + 64 < 2048) loadc(kc + 64);  // prefetch hides under compute

    // S = Q K^T : s[f] holds rows lg*4+r, cols f*16+lr (unscaled)
    f32x4 s[4];
    __builtin_amdgcn_s_setprio(1);
#pragma unroll
    for (int f = 0; f < 4; ++f) {
      s[f] = fz;
#pragma unroll
      for (int ks = 0; ks < 2; ++ks) {
        s16x8 kbh = *(const s16x8*)&Ksh[SWZ(f * 16 + lr, ks * 32 + lg * 8)];
        s16x8 kbl = *(const s16x8*)&Ksl[SWZ(f * 16 + lr, ks * 32 + lg * 8)];
        s[f] = MFMA(Qh[ks], kbh, s[f]);
        s[f] = MFMA(Qh[ks], kbl, s[f]);
        s[f] = MFMA(Ql[ks], kbh, s[f]);
      }
    }
    __builtin_amdgcn_s_setprio(0);

    // Online softmax (scale folded into exp via fmaf).
    float pm[4];
#pragma unroll
    for (int r = 0; r < 4; ++r)
      pm[r] = fmaxf(fmaxf(s[0][r], s[1][r]), fmaxf(s[2][r], s[3][r]));
#pragma unroll
    for (int msk = 1; msk < 16; msk <<= 1)
#pragma unroll
      for (int r = 0; r < 4; ++r)
        pm[r] = fmaxf(pm[r], __shfl_xor(pm[r], msk, 64));
    float fac[4], psum[4];
#pragma unroll
    for (int r = 0; r < 4; ++r) {
      float mn = fmaxf(mrow[r], pm[r] * 0.125f);
      fac[r] = __expf(mrow[r] - mn);
      mrow[r] = mn;
      psum[r] = 0.f;
    }
#pragma unroll
    for (int f = 0; f < 4; ++f)
#pragma unroll
      for (int r = 0; r < 4; ++r) {
        float pv = __expf(fmaf(s[f][r], 0.125f, -mrow[r]));
        u16 p_h = f2bf(pv);
        psum[r] += bf2f(p_h);  // denominator consistent with rounded P
        Ph[wave][SWZ(lg * 4 + r, f * 16 + lr)] = p_h;
      }
#pragma unroll
    for (int msk = 1; msk < 16; msk <<= 1)
#pragma unroll
      for (int r = 0; r < 4; ++r)
        psum[r] += __shfl_xor(psum[r], msk, 64);
#pragma unroll
    for (int r = 0; r < 4; ++r) {
      lrow[r] = lrow[r] * fac[r] + psum[r];
#pragma unroll
      for (int nf = 0; nf < 4; ++nf) o[nf][r] *= fac[r];
    }

    // O += P @ (Vh + Vl)
    s16x8 pah[2];
#pragma unroll
    for (int ks = 0; ks < 2; ++ks)
      pah[ks] = *(const s16x8*)&Ph[wave][SWZ(lr, ks * 32 + lg * 8)];
    __builtin_amdgcn_s_setprio(1);
#pragma unroll
    for (int nf = 0; nf < 4; ++nf) {
#pragma unroll
      for (int ks = 0; ks < 2; ++ks) {
        s16x8 vbh = *(const s16x8*)&Vsh[SWZ(nf * 16 + lr, ks * 32 + lg * 8)];
        s16x8 vbl = *(const s16x8*)&Vsl[SWZ(nf * 16 + lr, ks * 32 + lg * 8)];
        o[nf] = MFMA(pah[ks], vbh, o[nf]);
        o[nf] = MFMA(pah[ks], vbl, o[nf]);
      }
    }
    __builtin_amdgcn_s_setprio(0);
  }

  const float gv = gate[hh];
#pragma unroll
  for (int r = 0; r < 4; ++r) {
    float inv = gv / lrow[r];
    int row = bb * 2048 + q0 + wave * 16 + lg * 4 + r;
#pragma unroll
    for (int nf = 0; nf < 4; ++nf) {
      float v = o[nf][r] * inv;
      int col = hh * 64 + nf * 16 + lr;
      u16 vh16 = f2bf(v);
      aoh[(size_t)row * 768 + col] = vh16;
      aol[(size_t)row * 768 + col] = f2bf(v - bf2f(vh16));
    }
  }
}

// ---------------------------------------------------------------------------
extern "C" void kernel_launch(void* const* d_in, const int* in_sizes, int n_in,
                              void* d_out, int out_size, void* d_ws, size_t ws_size,
                              hipStream_t stream) {
  const float* x = (const float*)d_in[0];
  const float* w_qkv = (const float*)d_in[1];
  const float* gate = (const float*)d_in[2];
  const float* w_proj = (const float*)d_in[3];
  const float* b_proj = (const float*)d_in[4];
  float* out = (float*)d_out;

  u16* p = (u16*)d_ws;
  u16* xh = p; p += (size_t)4096 * 768;
  u16* xl = p; p += (size_t)4096 * 768;
  u16* wqh = p; p += (size_t)2304 * 768;
  u16* wql = p; p += (size_t)2304 * 768;
  u16* wph = p; p += (size_t)768 * 768;
  u16* wpl = p; p += (size_t)768 * 768;
  u16* qh = p; p += (size_t)4096 * 2304;
  u16* ql = p; p += (size_t)4096 * 2304;
  u16* vth = p; p += (size_t)24 * 64 * 2048;
  u16* vtl = p; p += (size_t)24 * 64 * 2048;
  u16* aoh = p; p += (size_t)4096 * 768;
  u16* aol = p; p += (size_t)4096 * 768;

  split8<<<dim3(4096 * 768 / 8 / 256), dim3(256), 0, stream>>>(x, xh, xl, 4096 * 768 / 8);
  splitT<<<dim3(2304 / 32, 768 / 32), dim3(32, 8), 0, stream>>>(w_qkv, wqh, wql, 768, 2304);
  splitT<<<dim3(768 / 32, 768 / 32), dim3(32, 8), 0, stream>>>(w_proj, wph, wpl, 768, 768);

  gemm_split<0><<<dim3(2304 / 128, 4096 / 128), dim3(256), 0, stream>>>(
      xh, xl, wqh, wql, qh, ql, nullptr, nullptr, 2304, 768);

  vtrans<<<dim3(32, 12, 2), dim3(256), 0, stream>>>(qh, ql, vth, vtl);

  attn_split<<<dim3(32, 12, 2), dim3(256), 0, stream>>>(qh, ql, vth, vtl, gate, aoh, aol);

  gemm_split<1><<<dim3(768 / 128, 4096 / 128), dim3(256), 0, stream>>>(
      aoh, aol, wph, wpl, nullptr, nullptr, out, b_proj, 768, 768);
}